// Round 1
// baseline (1395.506 us; speedup 1.0000x reference)
//
#include <hip/hip_runtime.h>

// Problem constants (Attention_27668179320916)
#define Bn   2
#define Sn   512
#define DIMn 4096
#define HQn  32
#define HKVn 8
#define HDn  128
#define NPAIR 64                       // HD/2 rope pairs per head
#define SCALE 11.313708498984761f      // scores / (hd**-0.5) == * sqrt(128) (faithful to ref)

// ---------------------------------------------------------------------------
// SGEMM (fp32):  C[M,N] = A[M,Kd] * W[N,Kd]^T      (both operands K-contiguous)
// CM,CN in {1,2}: tile BM=CM*64, BN=CN*64, BK=16, 256 threads,
// per-thread micro-tile (CM*4) x (CN*4). blockIdx.z selects (W0,C0)/(W1,C1)
// so K-proj and V-proj fuse into one 512-block launch.
// ---------------------------------------------------------------------------
template<int CM, int CN>
__global__ __launch_bounds__(256, 2) void sgemm_nt(
    const float* __restrict__ A,
    const float* __restrict__ W0, float* __restrict__ C0,
    const float* __restrict__ W1, float* __restrict__ C1,
    int M, int N, int Kd)
{
  constexpr int BM = CM * 64;
  constexpr int BN = CN * 64;
  constexpr int BK = 16;
  const float* __restrict__ W = (blockIdx.z == 0) ? W0 : W1;
  float* __restrict__ C = (blockIdx.z == 0) ? C0 : C1;

  __shared__ __align__(16) float As[BK][BM + 4];   // transposed: [k][m], row stride 16B-aligned
  __shared__ __align__(16) float Ws[BK][BN + 4];

  const int tid = threadIdx.x;
  const int tx = tid & 15;     // col group
  const int ty = tid >> 4;     // row group
  const int bm = blockIdx.y * BM;
  const int bn = blockIdx.x * BN;

  float acc[CM * 4][CN * 4];
#pragma unroll
  for (int i = 0; i < CM * 4; ++i)
#pragma unroll
    for (int j = 0; j < CN * 4; ++j) acc[i][j] = 0.f;

  for (int k0 = 0; k0 < Kd; k0 += BK) {
    // stage A tile (BM x BK) -> As[k][m]   (BM/64 float4 per thread, coalesced)
#pragma unroll
    for (int j = 0; j < CM; ++j) {
      int idx = j * 256 + tid;
      int row = idx >> 2;
      int k4  = idx & 3;
      float4 v = *(const float4*)(A + (size_t)(bm + row) * Kd + k0 + k4 * 4);
      As[k4 * 4 + 0][row] = v.x; As[k4 * 4 + 1][row] = v.y;
      As[k4 * 4 + 2][row] = v.z; As[k4 * 4 + 3][row] = v.w;
    }
#pragma unroll
    for (int j = 0; j < CN; ++j) {
      int idx = j * 256 + tid;
      int row = idx >> 2;
      int k4  = idx & 3;
      float4 v = *(const float4*)(W + (size_t)(bn + row) * Kd + k0 + k4 * 4);
      Ws[k4 * 4 + 0][row] = v.x; Ws[k4 * 4 + 1][row] = v.y;
      Ws[k4 * 4 + 2][row] = v.z; Ws[k4 * 4 + 3][row] = v.w;
    }
    __syncthreads();
#pragma unroll
    for (int k = 0; k < BK; ++k) {
      float a_[CM * 4], b_[CN * 4];
#pragma unroll
      for (int cm = 0; cm < CM; ++cm) {   // broadcast reads (4 unique/wave)
        float4 v = *(const float4*)&As[k][cm * 64 + ty * 4];
        a_[cm * 4 + 0] = v.x; a_[cm * 4 + 1] = v.y;
        a_[cm * 4 + 2] = v.z; a_[cm * 4 + 3] = v.w;
      }
#pragma unroll
      for (int cn = 0; cn < CN; ++cn) {   // 16 contiguous 16B chunks/wave
        float4 v = *(const float4*)&Ws[k][cn * 64 + tx * 4];
        b_[cn * 4 + 0] = v.x; b_[cn * 4 + 1] = v.y;
        b_[cn * 4 + 2] = v.z; b_[cn * 4 + 3] = v.w;
      }
#pragma unroll
      for (int i = 0; i < CM * 4; ++i)
#pragma unroll
        for (int j = 0; j < CN * 4; ++j)
          acc[i][j] = fmaf(a_[i], b_[j], acc[i][j]);
    }
    __syncthreads();
  }

#pragma unroll
  for (int cm = 0; cm < CM; ++cm)
#pragma unroll
    for (int r = 0; r < 4; ++r) {
      int row = bm + cm * 64 + ty * 4 + r;
#pragma unroll
      for (int cn = 0; cn < CN; ++cn) {
        float4 o;
        o.x = acc[cm * 4 + r][cn * 4 + 0]; o.y = acc[cm * 4 + r][cn * 4 + 1];
        o.z = acc[cm * 4 + r][cn * 4 + 2]; o.w = acc[cm * 4 + r][cn * 4 + 3];
        *(float4*)(C + (size_t)row * N + bn + cn * 64 + tx * 4) = o;
      }
    }
}

// ---------------------------------------------------------------------------
// RoPE in-place on [B,S,NH,HD]; pair p = ((b*S+s)*NH+h)*64 + i  -> elems 2p,2p+1
// positions from storage_idx (== arange(S) in this problem).
// ---------------------------------------------------------------------------
template<int NH>
__global__ void rope_kernel(float* __restrict__ T,
                            const float* __restrict__ fc, const float* __restrict__ fs,
                            const int* __restrict__ sidx, int npairs)
{
  int p = blockIdx.x * blockDim.x + threadIdx.x;
  if (p >= npairs) return;
  int i = p & (NPAIR - 1);
  int sh = p >> 6;                   // (b*S+s)*NH + h
  int srow = sh / NH;                // b*S + s   (NH is power of two)
  int s = srow & (Sn - 1);
  int pos = sidx[s];
  float c  = fc[pos * NPAIR + i];
  float sn = fs[pos * NPAIR + i];
  float2* T2 = (float2*)T;
  float2 v = T2[p];
  float2 o;
  o.x = v.x * c - v.y * sn;
  o.y = v.x * sn + v.y * c;
  T2[p] = o;
}

// ---------------------------------------------------------------------------
// Flash-style causal attention, fp32.
// Grid: B*HQ*(S/QT) blocks, 256 threads. Q-tile 64 rows; key tiles of 32.
// Keys >= storage position of the query row are masked (== mask tensor: the
// -1e9 rows make masked probs underflow to exactly 0, and cache slots >= 512
// are masked for every query, so the stale cache contributes exactly nothing).
// ---------------------------------------------------------------------------
#define QT 64
#define KT 32

__global__ __launch_bounds__(256, 2) void flash_attn(
    const float* __restrict__ Q, const float* __restrict__ K, const float* __restrict__ V,
    const int* __restrict__ sidx, float* __restrict__ O)
{
  const int bid = blockIdx.x;
  const int nqt = Sn / QT;                  // 8
  const int qt = bid & (nqt - 1);
  const int h  = (bid / nqt) & (HQn - 1);
  const int b  = bid / (nqt * HQn);
  const int q0 = qt * QT;
  const int hk = h >> 2;                    // GQA: rep = 4

  __shared__ __align__(16) float Qs[QT][HDn];        // 32 KB
  __shared__ __align__(16) float Ks[KT][HDn + 4];    // 16.5 KB (stride 132: BW-minimal banks)
  __shared__ __align__(16) float Vs[KT][HDn + 4];    // 16.5 KB
  __shared__ float Ps[QT][KT + 4];                   // scores -> probs
  __shared__ float row_m[QT], row_l[QT], row_c[QT];
  __shared__ int   qpos[QT];

  const int t  = threadIdx.x;
  const int rg = t >> 5;      // row group 0..7 (8 rows each)
  const int kx = t & 31;      // key index in S-phase / d4 index in PV & epilogue

#pragma unroll
  for (int j = 0; j < 8; ++j) {            // load Q tile (2048 float4)
    int idx = j * 256 + t;
    int r = idx >> 5, d4 = idx & 31;
    *(float4*)&Qs[r][d4 * 4] =
        *(const float4*)(Q + ((size_t)(b * Sn + q0 + r) * HQn + h) * HDn + d4 * 4);
  }
  if (t < QT) { qpos[t] = sidx[q0 + t]; row_m[t] = -3.0e38f; row_l[t] = 0.f; }

  float4 acc[8];
#pragma unroll
  for (int i = 0; i < 8; ++i) acc[i] = make_float4(0.f, 0.f, 0.f, 0.f);

  const int nkt = (q0 + QT) / KT;          // causal: only tiles with any valid key
  for (int kt = 0; kt < nkt; ++kt) {
    const int kbase = kt * KT;
    __syncthreads();                       // prev PV done before overwriting K/V/Ps
#pragma unroll
    for (int j = 0; j < 4; ++j) {          // load K,V tiles (1024 float4 each)
      int idx = j * 256 + t;
      int r = idx >> 5, d4 = idx & 31;
      size_t g = ((size_t)(b * Sn + kbase + r) * HKVn + hk) * HDn + d4 * 4;
      *(float4*)&Ks[r][d4 * 4] = *(const float4*)(K + g);
      *(float4*)&Vs[r][d4 * 4] = *(const float4*)(V + g);
    }
    __syncthreads();

    // ---- scores: thread = key kx, rows rg*8..rg*8+7 (register-blocked) ----
    {
      float4 sum[8];
#pragma unroll
      for (int i = 0; i < 8; ++i) sum[i] = make_float4(0.f, 0.f, 0.f, 0.f);
      for (int d4 = 0; d4 < 32; ++d4) {
        float4 kv = *(const float4*)&Ks[kx][d4 * 4];
#pragma unroll
        for (int i = 0; i < 8; ++i) {
          float4 qv = *(const float4*)&Qs[rg * 8 + i][d4 * 4];  // broadcast
          sum[i].x = fmaf(qv.x, kv.x, sum[i].x);
          sum[i].y = fmaf(qv.y, kv.y, sum[i].y);
          sum[i].z = fmaf(qv.z, kv.z, sum[i].z);
          sum[i].w = fmaf(qv.w, kv.w, sum[i].w);
        }
      }
      int kp = kbase + kx;                 // == storage position of this key
#pragma unroll
      for (int i = 0; i < 8; ++i) {
        int r = rg * 8 + i;
        float sc = (sum[i].x + sum[i].y + sum[i].z + sum[i].w) * SCALE;
        sc += (kp <= qpos[r]) ? 0.f : -1.0e9f;   // identical to mask tensor
        Ps[r][kx] = sc;
      }
    }
    __syncthreads();

    // ---- online softmax (wave 0, one thread per row) ----
    if (t < QT) {
      int r = t;
      float m_old = row_m[r];
      float mx = m_old;
#pragma unroll 8
      for (int k = 0; k < KT; ++k) mx = fmaxf(mx, Ps[r][k]);
      float c = __expf(m_old - mx);        // first tile: exp(-3e38) -> 0
      float l = row_l[r] * c;
      for (int k = 0; k < KT; ++k) {
        float p = __expf(Ps[r][k] - mx);   // masked: exp(~ -1e9) -> exactly 0
        Ps[r][k] = p;
        l += p;
      }
      row_m[r] = mx; row_l[r] = l; row_c[r] = c;
    }
    __syncthreads();

    // ---- PV accumulate: thread = d4 chunk kx, rows rg*8..+7 ----
    {
#pragma unroll
      for (int i = 0; i < 8; ++i) {
        float c = row_c[rg * 8 + i];
        acc[i].x *= c; acc[i].y *= c; acc[i].z *= c; acc[i].w *= c;
      }
      for (int k = 0; k < KT; ++k) {
        float4 vv = *(const float4*)&Vs[k][kx * 4];
#pragma unroll
        for (int i = 0; i < 8; ++i) {
          float p = Ps[rg * 8 + i][k];     // broadcast
          acc[i].x = fmaf(p, vv.x, acc[i].x);
          acc[i].y = fmaf(p, vv.y, acc[i].y);
          acc[i].z = fmaf(p, vv.z, acc[i].z);
          acc[i].w = fmaf(p, vv.w, acc[i].w);
        }
      }
    }
  }

  __syncthreads();
#pragma unroll
  for (int i = 0; i < 8; ++i) {
    int r = rg * 8 + i;
    float inv = 1.0f / row_l[r];
    float4 a = acc[i];
    a.x *= inv; a.y *= inv; a.z *= inv; a.w *= inv;
    *(float4*)(O + ((size_t)(b * Sn + q0 + r) * HQn + h) * HDn + kx * 4) = a;
  }
}

// ---------------------------------------------------------------------------
extern "C" void kernel_launch(void* const* d_in, const int* in_sizes, int n_in,
                              void* d_out, int out_size, void* d_ws, size_t ws_size,
                              hipStream_t stream)
{
  const float* x    = (const float*)d_in[0];
  const float* fc   = (const float*)d_in[1];
  const float* fs   = (const float*)d_in[2];
  // d_in[3] cache, d_in[4] mask: provably zero-contribution (see flash_attn comment)
  const int*   sidx = (const int*)d_in[5];
  const float* wq   = (const float*)d_in[6];
  const float* wk   = (const float*)d_in[7];
  const float* wv   = (const float*)d_in[8];
  const float* wo   = (const float*)d_in[9];
  float* out = (float*)d_out;

  const int M = Bn * Sn;                         // 1024
  float* Qw = (float*)d_ws;                      // [B,S,HQ,HD]  16 MB
  float* Kw = Qw + (size_t)M * HQn * HDn;        // [B,S,HKV,HD]  4 MB
  float* Vw = Kw + (size_t)M * HKVn * HDn;       //               4 MB
  float* Aw = Vw + (size_t)M * HKVn * HDn;       // attn out     16 MB

  // Q projection: 1024 x 4096 x 4096   (512 blocks, 2/CU)
  sgemm_nt<2, 1><<<dim3(DIMn / 64, M / 128, 1), 256, 0, stream>>>(
      x, wq, Qw, wq, Qw, M, DIMn, DIMn);
  // K and V projections fused via gridDim.z: 2 x (1024 x 1024 x 4096)
  sgemm_nt<1, 1><<<dim3((HKVn * HDn) / 64, M / 64, 2), 256, 0, stream>>>(
      x, wk, Kw, wv, Vw, M, HKVn * HDn, DIMn);
  // RoPE on Q and K
  rope_kernel<HQn><<<(M * HQn * NPAIR) / 256, 256, 0, stream>>>(
      Qw, fc, fs, sidx, M * HQn * NPAIR);
  rope_kernel<HKVn><<<(M * HKVn * NPAIR) / 256, 256, 0, stream>>>(
      Kw, fc, fs, sidx, M * HKVn * NPAIR);
  // causal GQA attention
  flash_attn<<<Bn * HQn * (Sn / QT), 256, 0, stream>>>(Qw, Kw, Vw, sidx, Aw);
  // output projection: 1024 x 4096 x 4096 -> d_out
  sgemm_nt<2, 1><<<dim3(DIMn / 64, M / 128, 1), 256, 0, stream>>>(
      Aw, wo, out, wo, out, M, DIMn, DIMn);
}

// Round 2
// 805.011 us; speedup vs baseline: 1.7335x; 1.7335x over previous
//
#include <hip/hip_runtime.h>

// Problem constants (Attention_27668179320916)
#define Bn   2
#define Sn   512
#define DIMn 4096
#define HQn  32
#define HKVn 8
#define HDn  128
#define NPAIR 64
#define SCALE 11.313708498984761f      // scores / (hd**-0.5) == * sqrt(128) (faithful to ref)

typedef short bf16x8 __attribute__((ext_vector_type(8)));
typedef float f32x4 __attribute__((ext_vector_type(4)));
typedef unsigned short ushort8 __attribute__((ext_vector_type(8)));

__device__ __forceinline__ unsigned short f2bf_rne(float f) {
  unsigned u = __builtin_bit_cast(unsigned, f);
  u += 0x7fffu + ((u >> 16) & 1u);
  return (unsigned short)(u >> 16);
}
__device__ __forceinline__ float bf2f(unsigned short h) {
  unsigned u = ((unsigned)h) << 16;
  return __builtin_bit_cast(float, u);
}

// ---------------------------------------------------------------------------
// MFMA GEMM: C[M,N] fp32 = A[M,Kd] * W[N,Kd]^T, fp32 inputs converted to bf16
// in-register during staging.
//   SPLIT=true : hi/lo split-bf16, 3 MFMAs/product (~2^-17 precision) — for
//                Q-proj / K-proj where score*sqrt(128) amplifies error.
//   SPLIT=false: plain bf16 (hi only), KSTEP=64, 2 k-slices/step.
// Tile 128x128, 4 waves of 64x64. LDS [128][64] bf16 per operand; 16B chunk
// at (row r, chunk c) stored at slot c^(r&7): 128B rows span all 32 banks ->
// reads and writes hit the LDS bandwidth floor (no conflicts).
// ---------------------------------------------------------------------------
template<bool SPLIT>
__global__ __launch_bounds__(256, 2) void gemm_mfma(
    const float* __restrict__ A, const float* __restrict__ W,
    float* __restrict__ C, int Kd, int N)
{
  constexpr int KSTEP = SPLIT ? 32 : 64;
  constexpr int UNITS = SPLIT ? 1024 : 2048;  // 8-float source units per tile-pair
  constexpr int UPT   = UNITS / 256;          // units per thread (4 or 8)
  constexpr int UPERMAT = UNITS / 2;
  constexpr int CPR   = SPLIT ? 4 : 8;        // source chunk-cols per row

  __shared__ __align__(16) unsigned short As[128 * 64];
  __shared__ __align__(16) unsigned short Bs[128 * 64];

  const int t  = threadIdx.x;
  const int bm = blockIdx.y * 128;
  const int bn = blockIdx.x * 128;

  // ---- staging descriptors (computed once) ----
  const float* gsrc[UPT];
  unsigned short* ldst[UPT];
  #pragma unroll
  for (int i = 0; i < UPT; ++i) {
    int u = i * 256 + t;
    bool isW = (u >= UPERMAT);
    int uu = isW ? u - UPERMAT : u;
    int r = uu / CPR;
    int c = uu % CPR;
    gsrc[i] = (isW ? W + (size_t)(bn + r) * Kd : A + (size_t)(bm + r) * Kd) + c * 8;
    int slot = c ^ (r & 7);
    ldst[i] = (isW ? Bs : As) + r * 64 + slot * 8;
  }

  // ---- fragment-read geometry ----
  const int lane = t & 63;
  const int w  = t >> 6;
  const int wr = w >> 1, wc = w & 1;            // wave -> 64x64 quadrant
  const int rl = lane & 15, kh = lane >> 4;     // frag row / k-half
  const int slotF = kh ^ (rl & 7);              // same for every fm (16-aligned)
  const unsigned short* ap = As + (wr * 64 + rl) * 64 + slotF * 8;
  const unsigned short* bp = Bs + (wc * 64 + rl) * 64 + slotF * 8;

  f32x4 acc[4][4];
  #pragma unroll
  for (int i = 0; i < 4; ++i)
  #pragma unroll
    for (int j = 0; j < 4; ++j) acc[i][j] = (f32x4){0.f, 0.f, 0.f, 0.f};

  float4 fbuf[UPT][2];
  #pragma unroll
  for (int i = 0; i < UPT; ++i) {               // prologue loads (k0 = 0)
    fbuf[i][0] = *(const float4*)(gsrc[i]);
    fbuf[i][1] = *(const float4*)(gsrc[i] + 4);
  }

  for (int k0 = 0; k0 < Kd; k0 += KSTEP) {
    // convert staged regs -> bf16 chunks (sits after prev compute; loads had
    // the whole previous compute phase to land)
    ushort8 hc[UPT], lc[UPT];
    #pragma unroll
    for (int i = 0; i < UPT; ++i) {
      float xv[8];
      xv[0] = fbuf[i][0].x; xv[1] = fbuf[i][0].y; xv[2] = fbuf[i][0].z; xv[3] = fbuf[i][0].w;
      xv[4] = fbuf[i][1].x; xv[5] = fbuf[i][1].y; xv[6] = fbuf[i][1].z; xv[7] = fbuf[i][1].w;
      #pragma unroll
      for (int j = 0; j < 8; ++j) {
        unsigned short hh = f2bf_rne(xv[j]);
        hc[i][j] = hh;
        if constexpr (SPLIT) lc[i][j] = f2bf_rne(xv[j] - bf2f(hh));
      }
    }
    __syncthreads();                            // prev tile fully consumed
    #pragma unroll
    for (int i = 0; i < UPT; ++i) {
      *(ushort8*)ldst[i] = hc[i];
      if constexpr (SPLIT)
        *(ushort8*)(((uintptr_t)(void*)ldst[i]) ^ 64) = lc[i];   // lo at slot^4
    }
    __syncthreads();                            // tile ready

    if (k0 + KSTEP < Kd) {                      // prefetch next tile (overlaps MFMA)
      #pragma unroll
      for (int i = 0; i < UPT; ++i) {
        fbuf[i][0] = *(const float4*)(gsrc[i] + k0 + KSTEP);
        fbuf[i][1] = *(const float4*)(gsrc[i] + k0 + KSTEP + 4);
      }
    }

    // ---- fragments + MFMA ----
    bf16x8 ah[4], al[4], bh[4], bl[4];
    #pragma unroll
    for (int f = 0; f < 4; ++f) {
      ah[f] = *(const bf16x8*)(ap + f * 1024);
      al[f] = *(const bf16x8*)(((uintptr_t)(const void*)(ap + f * 1024)) ^ 64);
      bh[f] = *(const bf16x8*)(bp + f * 1024);
      bl[f] = *(const bf16x8*)(((uintptr_t)(const void*)(bp + f * 1024)) ^ 64);
    }
    #pragma unroll
    for (int fm = 0; fm < 4; ++fm)
    #pragma unroll
      for (int fn = 0; fn < 4; ++fn) {
        if constexpr (SPLIT) {
          // (ah+al)*(bh+bl) dropping al*bl (~2^-18): 3 MFMAs
          acc[fm][fn] = __builtin_amdgcn_mfma_f32_16x16x32_bf16(ah[fm], bh[fn], acc[fm][fn], 0, 0, 0);
          acc[fm][fn] = __builtin_amdgcn_mfma_f32_16x16x32_bf16(al[fm], bh[fn], acc[fm][fn], 0, 0, 0);
          acc[fm][fn] = __builtin_amdgcn_mfma_f32_16x16x32_bf16(ah[fm], bl[fn], acc[fm][fn], 0, 0, 0);
        } else {
          // two k-slices of the 64-wide step
          acc[fm][fn] = __builtin_amdgcn_mfma_f32_16x16x32_bf16(ah[fm], bh[fn], acc[fm][fn], 0, 0, 0);
          acc[fm][fn] = __builtin_amdgcn_mfma_f32_16x16x32_bf16(al[fm], bl[fn], acc[fm][fn], 0, 0, 0);
        }
      }
  }

  // ---- epilogue: C/D layout col=lane&15, row=(lane>>4)*4+reg (m89-verified) ----
  const int crow0 = bm + wr * 64 + kh * 4;
  const int ccol0 = bn + wc * 64 + rl;
  #pragma unroll
  for (int fm = 0; fm < 4; ++fm)
  #pragma unroll
    for (int fn = 0; fn < 4; ++fn)
    #pragma unroll
      for (int j = 0; j < 4; ++j)
        C[(size_t)(crow0 + fm * 16 + j) * N + ccol0 + fn * 16] = acc[fm][fn][j];
}

// ---------------------------------------------------------------------------
// RoPE in-place on [B,S,NH,HD] (unchanged from round 1)
// ---------------------------------------------------------------------------
template<int NH>
__global__ void rope_kernel(float* __restrict__ T,
                            const float* __restrict__ fc, const float* __restrict__ fs,
                            const int* __restrict__ sidx, int npairs)
{
  int p = blockIdx.x * blockDim.x + threadIdx.x;
  if (p >= npairs) return;
  int i = p & (NPAIR - 1);
  int sh = p >> 6;
  int srow = sh / NH;
  int s = srow & (Sn - 1);
  int pos = sidx[s];
  float c  = fc[pos * NPAIR + i];
  float sn = fs[pos * NPAIR + i];
  float2* T2 = (float2*)T;
  float2 v = T2[p];
  float2 o;
  o.x = v.x * c - v.y * sn;
  o.y = v.x * sn + v.y * c;
  T2[p] = o;
}

// ---------------------------------------------------------------------------
// Flash-style causal attention, fp32 (unchanged from round 1 — passed).
// Masked scores underflow to exactly 0 after exp; stale cache contributes
// exactly nothing, so cache/mask tensors are never read.
// ---------------------------------------------------------------------------
#define QT 64
#define KT 32

__global__ __launch_bounds__(256, 2) void flash_attn(
    const float* __restrict__ Q, const float* __restrict__ K, const float* __restrict__ V,
    const int* __restrict__ sidx, float* __restrict__ O)
{
  const int bid = blockIdx.x;
  const int nqt = Sn / QT;
  const int qt = bid & (nqt - 1);
  const int h  = (bid / nqt) & (HQn - 1);
  const int b  = bid / (nqt * HQn);
  const int q0 = qt * QT;
  const int hk = h >> 2;

  __shared__ __align__(16) float Qs[QT][HDn];
  __shared__ __align__(16) float Ks[KT][HDn + 4];
  __shared__ __align__(16) float Vs[KT][HDn + 4];
  __shared__ float Ps[QT][KT + 4];
  __shared__ float row_m[QT], row_l[QT], row_c[QT];
  __shared__ int   qpos[QT];

  const int t  = threadIdx.x;
  const int rg = t >> 5;
  const int kx = t & 31;

#pragma unroll
  for (int j = 0; j < 8; ++j) {
    int idx = j * 256 + t;
    int r = idx >> 5, d4 = idx & 31;
    *(float4*)&Qs[r][d4 * 4] =
        *(const float4*)(Q + ((size_t)(b * Sn + q0 + r) * HQn + h) * HDn + d4 * 4);
  }
  if (t < QT) { qpos[t] = sidx[q0 + t]; row_m[t] = -3.0e38f; row_l[t] = 0.f; }

  float4 acc[8];
#pragma unroll
  for (int i = 0; i < 8; ++i) acc[i] = make_float4(0.f, 0.f, 0.f, 0.f);

  const int nkt = (q0 + QT) / KT;
  for (int kt = 0; kt < nkt; ++kt) {
    const int kbase = kt * KT;
    __syncthreads();
#pragma unroll
    for (int j = 0; j < 4; ++j) {
      int idx = j * 256 + t;
      int r = idx >> 5, d4 = idx & 31;
      size_t g = ((size_t)(b * Sn + kbase + r) * HKVn + hk) * HDn + d4 * 4;
      *(float4*)&Ks[r][d4 * 4] = *(const float4*)(K + g);
      *(float4*)&Vs[r][d4 * 4] = *(const float4*)(V + g);
    }
    __syncthreads();

    {
      float4 sum[8];
#pragma unroll
      for (int i = 0; i < 8; ++i) sum[i] = make_float4(0.f, 0.f, 0.f, 0.f);
      for (int d4 = 0; d4 < 32; ++d4) {
        float4 kv = *(const float4*)&Ks[kx][d4 * 4];
#pragma unroll
        for (int i = 0; i < 8; ++i) {
          float4 qv = *(const float4*)&Qs[rg * 8 + i][d4 * 4];
          sum[i].x = fmaf(qv.x, kv.x, sum[i].x);
          sum[i].y = fmaf(qv.y, kv.y, sum[i].y);
          sum[i].z = fmaf(qv.z, kv.z, sum[i].z);
          sum[i].w = fmaf(qv.w, kv.w, sum[i].w);
        }
      }
      int kp = kbase + kx;
#pragma unroll
      for (int i = 0; i < 8; ++i) {
        int r = rg * 8 + i;
        float sc = (sum[i].x + sum[i].y + sum[i].z + sum[i].w) * SCALE;
        sc += (kp <= qpos[r]) ? 0.f : -1.0e9f;
        Ps[r][kx] = sc;
      }
    }
    __syncthreads();

    if (t < QT) {
      int r = t;
      float m_old = row_m[r];
      float mx = m_old;
#pragma unroll 8
      for (int k = 0; k < KT; ++k) mx = fmaxf(mx, Ps[r][k]);
      float c = __expf(m_old - mx);
      float l = row_l[r] * c;
      for (int k = 0; k < KT; ++k) {
        float p = __expf(Ps[r][k] - mx);
        Ps[r][k] = p;
        l += p;
      }
      row_m[r] = mx; row_l[r] = l; row_c[r] = c;
    }
    __syncthreads();

    {
#pragma unroll
      for (int i = 0; i < 8; ++i) {
        float c = row_c[rg * 8 + i];
        acc[i].x *= c; acc[i].y *= c; acc[i].z *= c; acc[i].w *= c;
      }
      for (int k = 0; k < KT; ++k) {
        float4 vv = *(const float4*)&Vs[k][kx * 4];
#pragma unroll
        for (int i = 0; i < 8; ++i) {
          float p = Ps[rg * 8 + i][k];
          acc[i].x = fmaf(p, vv.x, acc[i].x);
          acc[i].y = fmaf(p, vv.y, acc[i].y);
          acc[i].z = fmaf(p, vv.z, acc[i].z);
          acc[i].w = fmaf(p, vv.w, acc[i].w);
        }
      }
    }
  }

  __syncthreads();
#pragma unroll
  for (int i = 0; i < 8; ++i) {
    int r = rg * 8 + i;
    float inv = 1.0f / row_l[r];
    float4 a = acc[i];
    a.x *= inv; a.y *= inv; a.z *= inv; a.w *= inv;
    *(float4*)(O + ((size_t)(b * Sn + q0 + r) * HQn + h) * HDn + kx * 4) = a;
  }
}

// ---------------------------------------------------------------------------
extern "C" void kernel_launch(void* const* d_in, const int* in_sizes, int n_in,
                              void* d_out, int out_size, void* d_ws, size_t ws_size,
                              hipStream_t stream)
{
  const float* x    = (const float*)d_in[0];
  const float* fc   = (const float*)d_in[1];
  const float* fs   = (const float*)d_in[2];
  const int*   sidx = (const int*)d_in[5];
  const float* wq   = (const float*)d_in[6];
  const float* wk   = (const float*)d_in[7];
  const float* wv   = (const float*)d_in[8];
  const float* wo   = (const float*)d_in[9];
  float* out = (float*)d_out;

  const int M = Bn * Sn;                         // 1024
  float* Qw = (float*)d_ws;                      // 16 MB
  float* Kw = Qw + (size_t)M * HQn * HDn;        //  4 MB
  float* Vw = Kw + (size_t)M * HKVn * HDn;       //  4 MB
  float* Aw = Vw + (size_t)M * HKVn * HDn;       // 16 MB

  // Q-proj (split-bf16): 1024 x 4096 x 4096
  gemm_mfma<true><<<dim3(DIMn / 128, M / 128), 256, 0, stream>>>(x, wq, Qw, DIMn, DIMn);
  // K-proj (split-bf16): 1024 x 1024 x 4096
  gemm_mfma<true><<<dim3((HKVn * HDn) / 128, M / 128), 256, 0, stream>>>(x, wk, Kw, DIMn, HKVn * HDn);
  // V-proj (plain bf16): 1024 x 1024 x 4096
  gemm_mfma<false><<<dim3((HKVn * HDn) / 128, M / 128), 256, 0, stream>>>(x, wv, Vw, DIMn, HKVn * HDn);
  // RoPE
  rope_kernel<HQn><<<(M * HQn * NPAIR) / 256, 256, 0, stream>>>(Qw, fc, fs, sidx, M * HQn * NPAIR);
  rope_kernel<HKVn><<<(M * HKVn * NPAIR) / 256, 256, 0, stream>>>(Kw, fc, fs, sidx, M * HKVn * NPAIR);
  // attention
  flash_attn<<<Bn * HQn * (Sn / QT), 256, 0, stream>>>(Qw, Kw, Vw, sidx, Aw);
  // O-proj (plain bf16): 1024 x 4096 x 4096
  gemm_mfma<false><<<dim3(DIMn / 128, M / 128), 256, 0, stream>>>(Aw, wo, out, DIMn, DIMn);
}

// Round 3
// 494.012 us; speedup vs baseline: 2.8248x; 1.6295x over previous
//
#include <hip/hip_runtime.h>

// Problem constants (Attention_27668179320916)
#define Bn   2
#define Sn   512
#define DIMn 4096
#define HQn  32
#define HKVn 8
#define HDn  128
#define NPAIR 64
#define SCALE 11.313708498984761f      // scores / (hd**-0.5) == * sqrt(128) (faithful to ref)

typedef short bf16x8 __attribute__((ext_vector_type(8)));
typedef float f32x4 __attribute__((ext_vector_type(4)));
typedef unsigned short ushort8 __attribute__((ext_vector_type(8)));

__device__ __forceinline__ unsigned short f2bf_rne(float f) {
  unsigned u = __builtin_bit_cast(unsigned, f);
  u += 0x7fffu + ((u >> 16) & 1u);
  return (unsigned short)(u >> 16);
}

// ---------------------------------------------------------------------------
// MFMA GEMM: C[M,N] fp32 = A[M,Kd] * W[N,Kd]^T, fp32 -> bf16 in-register.
//   SPLIT=true : hi/lo split-bf16, 3 MFMAs/product (~2^-17 eff. precision)
//   SPLIT=false: plain bf16 (RNE), KSTEP=64, 2 k-slices
// BM=64, BN template (128 or 64), 256 threads = 4 waves (2x2), each wave a
// 32 x BN/2 sub-tile (fm=2, fn=BN/32 frags of 16x16x32).
// LDS: unified Ls[2 buffers][(BM+BN) rows][64 ushorts]; 16B chunk c of row r
// at slot c^(r&7)  -> every row spans all 32 banks (BW-floor reads+writes).
// SPLIT: hi chunks at slot, lo at byte^64. Plain: slice-1 chunk = byte^64
// (identical addressing: (4+kh)^(r&7) == (kh^(r&7))^4).
// Pipeline: ONE barrier per k-step, double-buffered:
//   iter t: convert regs -> write buf[t&1]; issue loads tile t+1;
//           barrier; ds_read frags buf[t&1]; MFMA.
// Hazard proof: writes in iter t target the buffer last read in iter t-2,
// and barrier t-1 ordered those reads before these writes.
// blockIdx.z selects (W0,C0)/(W1,C1) so K-proj+V-proj fuse into one launch.
// ---------------------------------------------------------------------------
template<bool SPLIT, int BN>
__global__ __launch_bounds__(256, 2) void gemm_mfma(
    const float* __restrict__ A,
    const float* __restrict__ W0, float* __restrict__ C0,
    const float* __restrict__ W1, float* __restrict__ C1,
    int Kd, int N)
{
  constexpr int BM = 64;
  constexpr int KSTEP = SPLIT ? 32 : 64;
  constexpr int CPR = SPLIT ? 4 : 8;          // source 8-float chunks per row
  constexpr int AUNITS = BM * KSTEP / 8;
  constexpr int UNITS  = (BM + BN) * KSTEP / 8;
  constexpr int UPT = UNITS / 256;            // units per thread
  constexpr int FN = BN / 32;                 // B frags per wave
  constexpr int ROWS = BM + BN;

  __shared__ __align__(16) unsigned short Ls[2][ROWS * 64];

  const float* __restrict__ W = (blockIdx.z == 0) ? W0 : W1;
  float* __restrict__ Cp = (blockIdx.z == 0) ? C0 : C1;

  const int t  = threadIdx.x;
  const int bm = blockIdx.y * BM;
  const int bn = blockIdx.x * BN;

  // ---- staging descriptors ----
  const float* gsrc[UPT];
  int loff[UPT];
  #pragma unroll
  for (int i = 0; i < UPT; ++i) {
    int u = i * 256 + t;
    int row, c;
    if (u < AUNITS) {
      row = u / CPR; c = u % CPR;
      gsrc[i] = A + (size_t)(bm + row) * Kd + c * 8;
    } else {
      int v = u - AUNITS;
      int rr = v / CPR; c = v % CPR;
      row = BM + rr;
      gsrc[i] = W + (size_t)(bn + rr) * Kd + c * 8;
    }
    loff[i] = row * 64 + (c ^ (row & 7)) * 8;
  }

  // ---- fragment-read geometry ----
  const int lane = t & 63;
  const int w  = t >> 6;
  const int wr = w >> 1, wc = w & 1;
  const int rl = lane & 15, kh = lane >> 4;

  int aoff[2], boff[FN];
  #pragma unroll
  for (int fm = 0; fm < 2; ++fm) {
    int row = wr * 32 + fm * 16 + rl;
    aoff[fm] = row * 64 + (kh ^ (row & 7)) * 8;
  }
  #pragma unroll
  for (int fn = 0; fn < FN; ++fn) {
    int row = BM + wc * (BN / 2) + fn * 16 + rl;
    boff[fn] = row * 64 + (kh ^ (row & 7)) * 8;
  }

  f32x4 acc[2][FN];
  #pragma unroll
  for (int i = 0; i < 2; ++i)
  #pragma unroll
    for (int j = 0; j < FN; ++j) acc[i][j] = (f32x4){0.f, 0.f, 0.f, 0.f};

  // prologue: tile 0 -> regs
  float4 f0[UPT], f1[UPT];
  #pragma unroll
  for (int i = 0; i < UPT; ++i) {
    f0[i] = *(const float4*)(gsrc[i]);
    f1[i] = *(const float4*)(gsrc[i] + 4);
  }

  const int nt = Kd / KSTEP;
  for (int tt = 0; tt < nt; ++tt) {
    unsigned short* Lp = &Ls[tt & 1][0];

    // convert staged regs -> bf16, write LDS (buffer not read since iter t-2)
    #pragma unroll
    for (int i = 0; i < UPT; ++i) {
      float xv[8] = {f0[i].x, f0[i].y, f0[i].z, f0[i].w,
                     f1[i].x, f1[i].y, f1[i].z, f1[i].w};
      ushort8 hi, lo;
      #pragma unroll
      for (int j = 0; j < 8; ++j) {
        if constexpr (SPLIT) {
          // truncation split: hi+lo ~ exact to 2^-17 (lo mops up trunc error)
          unsigned u = __builtin_bit_cast(unsigned, xv[j]);
          hi[j] = (unsigned short)(u >> 16);
          float hf = __builtin_bit_cast(float, u & 0xffff0000u);
          lo[j] = (unsigned short)(__builtin_bit_cast(unsigned, xv[j] - hf) >> 16);
        } else {
          hi[j] = f2bf_rne(xv[j]);
          lo[j] = 0;
        }
      }
      *(ushort8*)(Lp + loff[i]) = hi;
      if constexpr (SPLIT)
        *(ushort8*)(((uintptr_t)(Lp + loff[i])) ^ 64) = lo;
    }
    // issue next-tile global loads (consumed at next iter's convert ->
    // covered by barrier + ds_read + MFMA phase)
    if (tt + 1 < nt) {
      #pragma unroll
      for (int i = 0; i < UPT; ++i) {
        f0[i] = *(const float4*)(gsrc[i] + (size_t)(tt + 1) * KSTEP);
        f1[i] = *(const float4*)(gsrc[i] + (size_t)(tt + 1) * KSTEP + 4);
      }
    }
    __syncthreads();                 // the ONLY barrier per k-step

    // ---- fragments + MFMA ----
    bf16x8 a0[2], a1[2], b0[FN], b1[FN];
    #pragma unroll
    for (int fm = 0; fm < 2; ++fm) {
      const unsigned short* p = Lp + aoff[fm];
      a0[fm] = *(const bf16x8*)p;
      a1[fm] = *(const bf16x8*)(((uintptr_t)p) ^ 64);   // lo (split) / slice1 (plain)
    }
    #pragma unroll
    for (int fn = 0; fn < FN; ++fn) {
      const unsigned short* p = Lp + boff[fn];
      b0[fn] = *(const bf16x8*)p;
      b1[fn] = *(const bf16x8*)(((uintptr_t)p) ^ 64);
    }
    #pragma unroll
    for (int fm = 0; fm < 2; ++fm)
    #pragma unroll
      for (int fn = 0; fn < FN; ++fn) {
        if constexpr (SPLIT) {
          acc[fm][fn] = __builtin_amdgcn_mfma_f32_16x16x32_bf16(a0[fm], b0[fn], acc[fm][fn], 0, 0, 0);
          acc[fm][fn] = __builtin_amdgcn_mfma_f32_16x16x32_bf16(a1[fm], b0[fn], acc[fm][fn], 0, 0, 0);
          acc[fm][fn] = __builtin_amdgcn_mfma_f32_16x16x32_bf16(a0[fm], b1[fn], acc[fm][fn], 0, 0, 0);
        } else {
          acc[fm][fn] = __builtin_amdgcn_mfma_f32_16x16x32_bf16(a0[fm], b0[fn], acc[fm][fn], 0, 0, 0);
          acc[fm][fn] = __builtin_amdgcn_mfma_f32_16x16x32_bf16(a1[fm], b1[fn], acc[fm][fn], 0, 0, 0);
        }
      }
  }

  // ---- epilogue: C/D layout col=lane&15, row=(lane>>4)*4+reg (m89) ----
  const int crow0 = bm + wr * 32 + kh * 4;
  const int ccol0 = bn + wc * (BN / 2) + rl;
  #pragma unroll
  for (int fm = 0; fm < 2; ++fm)
  #pragma unroll
    for (int fn = 0; fn < FN; ++fn)
    #pragma unroll
      for (int j = 0; j < 4; ++j)
        Cp[(size_t)(crow0 + fm * 16 + j) * N + ccol0 + fn * 16] = acc[fm][fn][j];
}

// ---------------------------------------------------------------------------
// RoPE in-place on [B,S,NH,HD]
// ---------------------------------------------------------------------------
template<int NH>
__global__ void rope_kernel(float* __restrict__ T,
                            const float* __restrict__ fc, const float* __restrict__ fs,
                            const int* __restrict__ sidx, int npairs)
{
  int p = blockIdx.x * blockDim.x + threadIdx.x;
  if (p >= npairs) return;
  int i = p & (NPAIR - 1);
  int sh = p >> 6;
  int srow = sh / NH;
  int s = srow & (Sn - 1);
  int pos = sidx[s];
  float c  = fc[pos * NPAIR + i];
  float sn = fs[pos * NPAIR + i];
  float2* T2 = (float2*)T;
  float2 v = T2[p];
  float2 o;
  o.x = v.x * c - v.y * sn;
  o.y = v.x * sn + v.y * c;
  T2[p] = o;
}

// ---------------------------------------------------------------------------
// Flash-style causal attention, fp32 (unchanged — passing). Masked scores
// underflow to exactly 0 after exp; stale cache contributes exactly nothing,
// so the cache/mask tensors are never read.
// ---------------------------------------------------------------------------
#define QT 64
#define KT 32

__global__ __launch_bounds__(256, 2) void flash_attn(
    const float* __restrict__ Q, const float* __restrict__ K, const float* __restrict__ V,
    const int* __restrict__ sidx, float* __restrict__ O)
{
  const int bid = blockIdx.x;
  const int nqt = Sn / QT;
  const int qt = bid & (nqt - 1);
  const int h  = (bid / nqt) & (HQn - 1);
  const int b  = bid / (nqt * HQn);
  const int q0 = qt * QT;
  const int hk = h >> 2;

  __shared__ __align__(16) float Qs[QT][HDn];
  __shared__ __align__(16) float Ks[KT][HDn + 4];
  __shared__ __align__(16) float Vs[KT][HDn + 4];
  __shared__ float Ps[QT][KT + 4];
  __shared__ float row_m[QT], row_l[QT], row_c[QT];
  __shared__ int   qpos[QT];

  const int t  = threadIdx.x;
  const int rg = t >> 5;
  const int kx = t & 31;

#pragma unroll
  for (int j = 0; j < 8; ++j) {
    int idx = j * 256 + t;
    int r = idx >> 5, d4 = idx & 31;
    *(float4*)&Qs[r][d4 * 4] =
        *(const float4*)(Q + ((size_t)(b * Sn + q0 + r) * HQn + h) * HDn + d4 * 4);
  }
  if (t < QT) { qpos[t] = sidx[q0 + t]; row_m[t] = -3.0e38f; row_l[t] = 0.f; }

  float4 acc[8];
#pragma unroll
  for (int i = 0; i < 8; ++i) acc[i] = make_float4(0.f, 0.f, 0.f, 0.f);

  const int nkt = (q0 + QT) / KT;
  for (int kt = 0; kt < nkt; ++kt) {
    const int kbase = kt * KT;
    __syncthreads();
#pragma unroll
    for (int j = 0; j < 4; ++j) {
      int idx = j * 256 + t;
      int r = idx >> 5, d4 = idx & 31;
      size_t g = ((size_t)(b * Sn + kbase + r) * HKVn + hk) * HDn + d4 * 4;
      *(float4*)&Ks[r][d4 * 4] = *(const float4*)(K + g);
      *(float4*)&Vs[r][d4 * 4] = *(const float4*)(V + g);
    }
    __syncthreads();

    {
      float4 sum[8];
#pragma unroll
      for (int i = 0; i < 8; ++i) sum[i] = make_float4(0.f, 0.f, 0.f, 0.f);
      for (int d4 = 0; d4 < 32; ++d4) {
        float4 kv = *(const float4*)&Ks[kx][d4 * 4];
#pragma unroll
        for (int i = 0; i < 8; ++i) {
          float4 qv = *(const float4*)&Qs[rg * 8 + i][d4 * 4];
          sum[i].x = fmaf(qv.x, kv.x, sum[i].x);
          sum[i].y = fmaf(qv.y, kv.y, sum[i].y);
          sum[i].z = fmaf(qv.z, kv.z, sum[i].z);
          sum[i].w = fmaf(qv.w, kv.w, sum[i].w);
        }
      }
      int kp = kbase + kx;
#pragma unroll
      for (int i = 0; i < 8; ++i) {
        int r = rg * 8 + i;
        float sc = (sum[i].x + sum[i].y + sum[i].z + sum[i].w) * SCALE;
        sc += (kp <= qpos[r]) ? 0.f : -1.0e9f;
        Ps[r][kx] = sc;
      }
    }
    __syncthreads();

    if (t < QT) {
      int r = t;
      float m_old = row_m[r];
      float mx = m_old;
#pragma unroll 8
      for (int k = 0; k < KT; ++k) mx = fmaxf(mx, Ps[r][k]);
      float c = __expf(m_old - mx);
      float l = row_l[r] * c;
      for (int k = 0; k < KT; ++k) {
        float p = __expf(Ps[r][k] - mx);
        Ps[r][k] = p;
        l += p;
      }
      row_m[r] = mx; row_l[r] = l; row_c[r] = c;
    }
    __syncthreads();

    {
#pragma unroll
      for (int i = 0; i < 8; ++i) {
        float c = row_c[rg * 8 + i];
        acc[i].x *= c; acc[i].y *= c; acc[i].z *= c; acc[i].w *= c;
      }
      for (int k = 0; k < KT; ++k) {
        float4 vv = *(const float4*)&Vs[k][kx * 4];
#pragma unroll
        for (int i = 0; i < 8; ++i) {
          float p = Ps[rg * 8 + i][k];
          acc[i].x = fmaf(p, vv.x, acc[i].x);
          acc[i].y = fmaf(p, vv.y, acc[i].y);
          acc[i].z = fmaf(p, vv.z, acc[i].z);
          acc[i].w = fmaf(p, vv.w, acc[i].w);
        }
      }
    }
  }

  __syncthreads();
#pragma unroll
  for (int i = 0; i < 8; ++i) {
    int r = rg * 8 + i;
    float inv = 1.0f / row_l[r];
    float4 a = acc[i];
    a.x *= inv; a.y *= inv; a.z *= inv; a.w *= inv;
    *(float4*)(O + ((size_t)(b * Sn + q0 + r) * HQn + h) * HDn + kx * 4) = a;
  }
}

// ---------------------------------------------------------------------------
extern "C" void kernel_launch(void* const* d_in, const int* in_sizes, int n_in,
                              void* d_out, int out_size, void* d_ws, size_t ws_size,
                              hipStream_t stream)
{
  const float* x    = (const float*)d_in[0];
  const float* fc   = (const float*)d_in[1];
  const float* fs   = (const float*)d_in[2];
  const int*   sidx = (const int*)d_in[5];
  const float* wq   = (const float*)d_in[6];
  const float* wk   = (const float*)d_in[7];
  const float* wv   = (const float*)d_in[8];
  const float* wo   = (const float*)d_in[9];
  float* out = (float*)d_out;

  const int M = Bn * Sn;                         // 1024
  float* Qw = (float*)d_ws;                      // 16 MB
  float* Kw = Qw + (size_t)M * HQn * HDn;        //  4 MB
  float* Vw = Kw + (size_t)M * HKVn * HDn;       //  4 MB
  float* Aw = Vw + (size_t)M * HKVn * HDn;       // 16 MB

  // Q-proj (split): 1024x4096x4096, 512 blocks (2/CU)
  gemm_mfma<true, 128><<<dim3(DIMn / 128, M / 64, 1), 256, 0, stream>>>(
      x, wq, Qw, wq, Qw, DIMn, DIMn);
  // K-proj + V-proj fused (split, BN=64): 2 x 1024x1024x4096, 512 blocks
  gemm_mfma<true, 64><<<dim3((HKVn * HDn) / 64, M / 64, 2), 256, 0, stream>>>(
      x, wk, Kw, wv, Vw, DIMn, HKVn * HDn);
  // RoPE
  rope_kernel<HQn><<<(M * HQn * NPAIR) / 256, 256, 0, stream>>>(
      Qw, fc, fs, sidx, M * HQn * NPAIR);
  rope_kernel<HKVn><<<(M * HKVn * NPAIR) / 256, 256, 0, stream>>>(
      Kw, fc, fs, sidx, M * HKVn * NPAIR);
  // attention
  flash_attn<<<Bn * HQn * (Sn / QT), 256, 0, stream>>>(Qw, Kw, Vw, sidx, Aw);
  // O-proj (plain bf16): 1024x4096x4096, 512 blocks
  gemm_mfma<false, 128><<<dim3(DIMn / 128, M / 64, 1), 256, 0, stream>>>(
      Aw, wo, out, wo, out, DIMn, DIMn);
}

// Round 4
// 366.549 us; speedup vs baseline: 3.8071x; 1.3477x over previous
//
#include <hip/hip_runtime.h>

// Problem constants (Attention_27668179320916)
#define Bn   2
#define Sn   512
#define DIMn 4096
#define HQn  32
#define HKVn 8
#define HDn  128
#define NPAIR 64
#define SCALE 11.313708498984761f      // scores / (hd**-0.5) == * sqrt(128) (faithful to ref)

typedef short bf16x8 __attribute__((ext_vector_type(8)));
typedef float f32x4 __attribute__((ext_vector_type(4)));
typedef unsigned short ushort8 __attribute__((ext_vector_type(8)));

__device__ __forceinline__ unsigned short f2bf_rne(float f) {
  unsigned u = __builtin_bit_cast(unsigned, f);
  u += 0x7fffu + ((u >> 16) & 1u);
  return (unsigned short)(u >> 16);
}
// truncation split: hi = trunc-bf16(x), lo = trunc-bf16(x-hi); hi+lo exact to ~2^-17
__device__ __forceinline__ void split_bf16(float x, unsigned short& hi, unsigned short& lo) {
  unsigned u = __builtin_bit_cast(unsigned, x);
  hi = (unsigned short)(u >> 16);
  float hf = __builtin_bit_cast(float, u & 0xffff0000u);
  lo = (unsigned short)(__builtin_bit_cast(unsigned, x - hf) >> 16);
}

// ---------------------------------------------------------------------------
// MFMA GEMM (unchanged from round 3 — passing): C = A * W^T, fp32->bf16 staged.
// ---------------------------------------------------------------------------
template<bool SPLIT, int BN>
__global__ __launch_bounds__(256, 2) void gemm_mfma(
    const float* __restrict__ A,
    const float* __restrict__ W0, float* __restrict__ C0,
    const float* __restrict__ W1, float* __restrict__ C1,
    int Kd, int N)
{
  constexpr int BM = 64;
  constexpr int KSTEP = SPLIT ? 32 : 64;
  constexpr int CPR = SPLIT ? 4 : 8;
  constexpr int AUNITS = BM * KSTEP / 8;
  constexpr int UNITS  = (BM + BN) * KSTEP / 8;
  constexpr int UPT = UNITS / 256;
  constexpr int FN = BN / 32;
  constexpr int ROWS = BM + BN;

  __shared__ __align__(16) unsigned short Ls[2][ROWS * 64];

  const float* __restrict__ W = (blockIdx.z == 0) ? W0 : W1;
  float* __restrict__ Cp = (blockIdx.z == 0) ? C0 : C1;

  const int t  = threadIdx.x;
  const int bm = blockIdx.y * BM;
  const int bn = blockIdx.x * BN;

  const float* gsrc[UPT];
  int loff[UPT];
  #pragma unroll
  for (int i = 0; i < UPT; ++i) {
    int u = i * 256 + t;
    int row, c;
    if (u < AUNITS) {
      row = u / CPR; c = u % CPR;
      gsrc[i] = A + (size_t)(bm + row) * Kd + c * 8;
    } else {
      int v = u - AUNITS;
      int rr = v / CPR; c = v % CPR;
      row = BM + rr;
      gsrc[i] = W + (size_t)(bn + rr) * Kd + c * 8;
    }
    loff[i] = row * 64 + (c ^ (row & 7)) * 8;
  }

  const int lane = t & 63;
  const int w  = t >> 6;
  const int wr = w >> 1, wc = w & 1;
  const int rl = lane & 15, kh = lane >> 4;

  int aoff[2], boff[FN];
  #pragma unroll
  for (int fm = 0; fm < 2; ++fm) {
    int row = wr * 32 + fm * 16 + rl;
    aoff[fm] = row * 64 + (kh ^ (row & 7)) * 8;
  }
  #pragma unroll
  for (int fn = 0; fn < FN; ++fn) {
    int row = BM + wc * (BN / 2) + fn * 16 + rl;
    boff[fn] = row * 64 + (kh ^ (row & 7)) * 8;
  }

  f32x4 acc[2][FN];
  #pragma unroll
  for (int i = 0; i < 2; ++i)
  #pragma unroll
    for (int j = 0; j < FN; ++j) acc[i][j] = (f32x4){0.f, 0.f, 0.f, 0.f};

  float4 f0[UPT], f1[UPT];
  #pragma unroll
  for (int i = 0; i < UPT; ++i) {
    f0[i] = *(const float4*)(gsrc[i]);
    f1[i] = *(const float4*)(gsrc[i] + 4);
  }

  const int nt = Kd / KSTEP;
  for (int tt = 0; tt < nt; ++tt) {
    unsigned short* Lp = &Ls[tt & 1][0];
    #pragma unroll
    for (int i = 0; i < UPT; ++i) {
      float xv[8] = {f0[i].x, f0[i].y, f0[i].z, f0[i].w,
                     f1[i].x, f1[i].y, f1[i].z, f1[i].w};
      ushort8 hi, lo;
      #pragma unroll
      for (int j = 0; j < 8; ++j) {
        if constexpr (SPLIT) {
          unsigned short h_, l_;
          split_bf16(xv[j], h_, l_);
          hi[j] = h_; lo[j] = l_;
        } else {
          hi[j] = f2bf_rne(xv[j]);
          lo[j] = 0;
        }
      }
      *(ushort8*)(Lp + loff[i]) = hi;
      if constexpr (SPLIT)
        *(ushort8*)(((uintptr_t)(Lp + loff[i])) ^ 64) = lo;
    }
    if (tt + 1 < nt) {
      #pragma unroll
      for (int i = 0; i < UPT; ++i) {
        f0[i] = *(const float4*)(gsrc[i] + (size_t)(tt + 1) * KSTEP);
        f1[i] = *(const float4*)(gsrc[i] + (size_t)(tt + 1) * KSTEP + 4);
      }
    }
    __syncthreads();

    bf16x8 a0[2], a1[2], b0[FN], b1[FN];
    #pragma unroll
    for (int fm = 0; fm < 2; ++fm) {
      const unsigned short* p = Lp + aoff[fm];
      a0[fm] = *(const bf16x8*)p;
      a1[fm] = *(const bf16x8*)(((uintptr_t)p) ^ 64);
    }
    #pragma unroll
    for (int fn = 0; fn < FN; ++fn) {
      const unsigned short* p = Lp + boff[fn];
      b0[fn] = *(const bf16x8*)p;
      b1[fn] = *(const bf16x8*)(((uintptr_t)p) ^ 64);
    }
    #pragma unroll
    for (int fm = 0; fm < 2; ++fm)
    #pragma unroll
      for (int fn = 0; fn < FN; ++fn) {
        if constexpr (SPLIT) {
          acc[fm][fn] = __builtin_amdgcn_mfma_f32_16x16x32_bf16(a0[fm], b0[fn], acc[fm][fn], 0, 0, 0);
          acc[fm][fn] = __builtin_amdgcn_mfma_f32_16x16x32_bf16(a1[fm], b0[fn], acc[fm][fn], 0, 0, 0);
          acc[fm][fn] = __builtin_amdgcn_mfma_f32_16x16x32_bf16(a0[fm], b1[fn], acc[fm][fn], 0, 0, 0);
        } else {
          acc[fm][fn] = __builtin_amdgcn_mfma_f32_16x16x32_bf16(a0[fm], b0[fn], acc[fm][fn], 0, 0, 0);
          acc[fm][fn] = __builtin_amdgcn_mfma_f32_16x16x32_bf16(a1[fm], b1[fn], acc[fm][fn], 0, 0, 0);
        }
      }
  }

  const int crow0 = bm + wr * 32 + kh * 4;
  const int ccol0 = bn + wc * (BN / 2) + rl;
  #pragma unroll
  for (int fm = 0; fm < 2; ++fm)
  #pragma unroll
    for (int fn = 0; fn < FN; ++fn)
    #pragma unroll
      for (int j = 0; j < 4; ++j)
        Cp[(size_t)(crow0 + fm * 16 + j) * N + ccol0 + fn * 16] = acc[fm][fn][j];
}

// ---------------------------------------------------------------------------
// MFMA flash attention, fused RoPE (Q and K), causal GQA.
// Grid: B*HQ*(S/64) blocks, 4 waves; wave w owns q-rows [q0+16w, q0+16w+16).
// Swapped QK^T: S^T = mfma(K,Q) -> lane(kh,rl) holds S[q=rl][kk=f*16+kh*4+r]
// fully in-register; softmax = in-lane ops + shfl_xor(16/32) over kh groups.
// PV: P (exp'd, bf16) is a valid A-frag IN-LANE under k-permutation
// sigma(kh,j)=f*16+kh*4+r; V staged TRANSPOSED (Vt[d][kk], pad 40) so B-frags
// are 2x ds_read_b64 of row d. A/B use the same sigma -> permutation cancels
// (same invariant the passing GEMM relies on).
// Q/K: trunc-split hi/lo bf16, 3 MFMAs (score*sqrt(128) is precision-critical).
// P/V: plain bf16 (error-tolerant). Masked scores underflow to exactly 0;
// stale cache slots are always masked => cache/mask tensors never read.
// K tiles double-buffered, ONE barrier per tile (same hazard proof as GEMM).
// ---------------------------------------------------------------------------
#define KT 32

__global__ __launch_bounds__(256, 2) void flash_attn_mfma(
    const float* __restrict__ Qg, const float* __restrict__ Kg, const float* __restrict__ Vg,
    const float* __restrict__ fc, const float* __restrict__ fs,
    const int* __restrict__ sidx, float* __restrict__ O)
{
  const int bid = blockIdx.x;
  const int qt = bid & 7;
  const int h  = (bid >> 3) & 31;
  const int b  = bid >> 8;
  const int q0 = qt * 64;
  const int hk = h >> 2;

  __shared__ __align__(16) unsigned short Ks[2][2][32][128];  // [buf][hi/lo][kk][d] swizzled
  __shared__ __align__(16) unsigned short Vt[2][128][40];     // [buf][d][kk], pad 40

  const int t = threadIdx.x;
  const int w = t >> 6;
  const int lane = t & 63;
  const int rl = lane & 15;
  const int kh = lane >> 4;

  const int qrow = q0 + w * 16 + rl;       // this lane's softmax q-row
  const int qp = sidx[qrow];

  // K staging: 2 units (row kr, 8-float chunk kc_); V staging: row kkv, 16 d's
  int kr[2], kc_[2];
  #pragma unroll
  for (int i = 0; i < 2; ++i) { int u = i * 256 + t; kr[i] = u >> 4; kc_[i] = u & 15; }
  const int kkv = t >> 3, dcv = t & 7;

  const int nkt = (q0 + 64) / KT;
  const int qmaxw = q0 + w * 16 + 15;

  float kreg[2][8]; float4 kc4[2], ks4[2];
  float vreg[16];

  // ---- prefetch tile 0 ----
  #pragma unroll
  for (int i = 0; i < 2; ++i) {
    const float* kp_ = Kg + ((size_t)(b * Sn + kr[i]) * HKVn + hk) * HDn + kc_[i] * 8;
    *(float4*)&kreg[i][0] = *(const float4*)kp_;
    *(float4*)&kreg[i][4] = *(const float4*)(kp_ + 4);
    int posk = sidx[kr[i]];
    kc4[i] = *(const float4*)(fc + (size_t)posk * NPAIR + kc_[i] * 4);
    ks4[i] = *(const float4*)(fs + (size_t)posk * NPAIR + kc_[i] * 4);
  }
  {
    const float* vp_ = Vg + ((size_t)(b * Sn + kkv) * HKVn + hk) * HDn + dcv * 16;
    #pragma unroll
    for (int i = 0; i < 4; ++i) *(float4*)&vreg[i * 4] = *(const float4*)(vp_ + i * 4);
  }

  // ---- Q -> B-frags, fused RoPE + trunc split (held in regs all block) ----
  bf16x8 qh[4], ql[4];
  {
    const float* qptr = Qg + ((size_t)(b * Sn + qrow) * HQn + h) * HDn;
    #pragma unroll
    for (int ds = 0; ds < 4; ++ds) {
      int d0 = ds * 32 + kh * 8;
      float4 u0 = *(const float4*)(qptr + d0);
      float4 u1 = *(const float4*)(qptr + d0 + 4);
      float4 c4 = *(const float4*)(fc + (size_t)qp * NPAIR + d0 / 2);
      float4 s4 = *(const float4*)(fs + (size_t)qp * NPAIR + d0 / 2);
      float v[8];
      v[0] = u0.x * c4.x - u0.y * s4.x;  v[1] = u0.x * s4.x + u0.y * c4.x;
      v[2] = u0.z * c4.y - u0.w * s4.y;  v[3] = u0.z * s4.y + u0.w * c4.y;
      v[4] = u1.x * c4.z - u1.y * s4.z;  v[5] = u1.x * s4.z + u1.y * c4.z;
      v[6] = u1.z * c4.w - u1.w * s4.w;  v[7] = u1.z * s4.w + u1.w * c4.w;
      #pragma unroll
      for (int j = 0; j < 8; ++j) {
        unsigned short h_, l_;
        split_bf16(v[j], h_, l_);
        qh[ds][j] = (short)h_; ql[ds][j] = (short)l_;
      }
    }
  }

  float m_run = -3.0e38f, l_run = 0.f;
  f32x4 acc_o[8];
  #pragma unroll
  for (int i = 0; i < 8; ++i) acc_o[i] = (f32x4){0.f, 0.f, 0.f, 0.f};

  for (int tt = 0; tt < nkt; ++tt) {
    const int kbase = tt * KT;
    const int buf = tt & 1;

    // ---- convert staged regs (RoPE on K) -> write LDS buf ----
    #pragma unroll
    for (int i = 0; i < 2; ++i) {
      float rv[8];
      rv[0] = kreg[i][0] * kc4[i].x - kreg[i][1] * ks4[i].x;
      rv[1] = kreg[i][0] * ks4[i].x + kreg[i][1] * kc4[i].x;
      rv[2] = kreg[i][2] * kc4[i].y - kreg[i][3] * ks4[i].y;
      rv[3] = kreg[i][2] * ks4[i].y + kreg[i][3] * kc4[i].y;
      rv[4] = kreg[i][4] * kc4[i].z - kreg[i][5] * ks4[i].z;
      rv[5] = kreg[i][4] * ks4[i].z + kreg[i][5] * kc4[i].z;
      rv[6] = kreg[i][6] * kc4[i].w - kreg[i][7] * ks4[i].w;
      rv[7] = kreg[i][6] * ks4[i].w + kreg[i][7] * kc4[i].w;
      ushort8 hi, lo;
      #pragma unroll
      for (int j = 0; j < 8; ++j) {
        unsigned short h_, l_;
        split_bf16(rv[j], h_, l_);
        hi[j] = h_; lo[j] = l_;
      }
      int slot = kc_[i] ^ (kr[i] & 15);
      *(ushort8*)&Ks[buf][0][kr[i]][slot * 8] = hi;
      *(ushort8*)&Ks[buf][1][kr[i]][slot * 8] = lo;
    }
    #pragma unroll
    for (int i = 0; i < 16; ++i)
      Vt[buf][dcv * 16 + i][kkv] = f2bf_rne(vreg[i]);

    // ---- prefetch next tile (lands during this tile's compute) ----
    if (tt + 1 < nkt) {
      const int kb = kbase + KT;
      #pragma unroll
      for (int i = 0; i < 2; ++i) {
        const float* kp_ = Kg + ((size_t)(b * Sn + kb + kr[i]) * HKVn + hk) * HDn + kc_[i] * 8;
        *(float4*)&kreg[i][0] = *(const float4*)kp_;
        *(float4*)&kreg[i][4] = *(const float4*)(kp_ + 4);
        int posk = sidx[kb + kr[i]];
        kc4[i] = *(const float4*)(fc + (size_t)posk * NPAIR + kc_[i] * 4);
        ks4[i] = *(const float4*)(fs + (size_t)posk * NPAIR + kc_[i] * 4);
      }
      const float* vp_ = Vg + ((size_t)(b * Sn + kb + kkv) * HKVn + hk) * HDn + dcv * 16;
      #pragma unroll
      for (int i = 0; i < 4; ++i) *(float4*)&vreg[i * 4] = *(const float4*)(vp_ + i * 4);
    }
    __syncthreads();                 // the ONLY barrier per tile

    if (kbase > qmaxw) continue;     // wave fully masked for this tile

    // ---- QK^T (swapped): S[q=rl][kk] ----
    float p[8];
    #pragma unroll
    for (int fm = 0; fm < 2; ++fm) {
      f32x4 accs = (f32x4){0.f, 0.f, 0.f, 0.f};
      #pragma unroll
      for (int ds = 0; ds < 4; ++ds) {
        int slot = (ds * 4 + kh) ^ rl;
        bf16x8 kH = *(const bf16x8*)&Ks[buf][0][fm * 16 + rl][slot * 8];
        bf16x8 kL = *(const bf16x8*)&Ks[buf][1][fm * 16 + rl][slot * 8];
        accs = __builtin_amdgcn_mfma_f32_16x16x32_bf16(kH, qh[ds], accs, 0, 0, 0);
        accs = __builtin_amdgcn_mfma_f32_16x16x32_bf16(kL, qh[ds], accs, 0, 0, 0);
        accs = __builtin_amdgcn_mfma_f32_16x16x32_bf16(kH, ql[ds], accs, 0, 0, 0);
      }
      #pragma unroll
      for (int r = 0; r < 4; ++r) {
        int kp = kbase + fm * 16 + kh * 4 + r;
        p[fm * 4 + r] = accs[r] * SCALE + ((kp <= qp) ? 0.f : -1.0e9f);
      }
    }

    // ---- online softmax: in-lane 8 + kh-group reduce (shfl_xor 16,32) ----
    float tmax = p[0];
    #pragma unroll
    for (int i = 1; i < 8; ++i) tmax = fmaxf(tmax, p[i]);
    tmax = fmaxf(tmax, __shfl_xor(tmax, 16));
    tmax = fmaxf(tmax, __shfl_xor(tmax, 32));
    float m_new = fmaxf(m_run, tmax);
    float crs = __expf(m_run - m_new);   // first real tile: exp(-3e38) -> 0
    m_run = m_new;
    float tsum = 0.f;
    bf16x8 pa;
    #pragma unroll
    for (int i = 0; i < 8; ++i) {
      float ev = __expf(p[i] - m_new);   // masked: exp(~-1e9) -> exactly 0
      tsum += ev;
      pa[i] = (short)f2bf_rne(ev);
    }
    tsum += __shfl_xor(tsum, 16);
    tsum += __shfl_xor(tsum, 32);
    l_run = l_run * crs + tsum;

    // rescale factors for this lane's OUTPUT rows (q = kh*4+r lives at lane rl=q)
    float cq[4];
    #pragma unroll
    for (int r = 0; r < 4; ++r) cq[r] = __shfl(crs, kh * 4 + r);

    // ---- PV: out[q][d] += P * V ----
    #pragma unroll
    for (int db = 0; db < 8; ++db) {
      short4 v0 = *(const short4*)&Vt[buf][db * 16 + rl][kh * 4];
      short4 v1 = *(const short4*)&Vt[buf][db * 16 + rl][16 + kh * 4];
      bf16x8 vb = {v0.x, v0.y, v0.z, v0.w, v1.x, v1.y, v1.z, v1.w};
      f32x4 a = acc_o[db];
      a[0] *= cq[0]; a[1] *= cq[1]; a[2] *= cq[2]; a[3] *= cq[3];
      acc_o[db] = __builtin_amdgcn_mfma_f32_16x16x32_bf16(pa, vb, a, 0, 0, 0);
    }
  }

  // ---- epilogue: divide by row-sum, store (coalesced: rl -> consecutive d) ----
  float lq[4];
  #pragma unroll
  for (int r = 0; r < 4; ++r) lq[r] = 1.0f / __shfl(l_run, kh * 4 + r);
  #pragma unroll
  for (int db = 0; db < 8; ++db)
  #pragma unroll
    for (int r = 0; r < 4; ++r) {
      int q = q0 + w * 16 + kh * 4 + r;
      O[((size_t)(b * Sn + q) * HQn + h) * HDn + db * 16 + rl] = acc_o[db][r] * lq[r];
    }
}

// ---------------------------------------------------------------------------
extern "C" void kernel_launch(void* const* d_in, const int* in_sizes, int n_in,
                              void* d_out, int out_size, void* d_ws, size_t ws_size,
                              hipStream_t stream)
{
  const float* x    = (const float*)d_in[0];
  const float* fc   = (const float*)d_in[1];
  const float* fs   = (const float*)d_in[2];
  const int*   sidx = (const int*)d_in[5];
  const float* wq   = (const float*)d_in[6];
  const float* wk   = (const float*)d_in[7];
  const float* wv   = (const float*)d_in[8];
  const float* wo   = (const float*)d_in[9];
  float* out = (float*)d_out;

  const int M = Bn * Sn;                         // 1024
  float* Qw = (float*)d_ws;                      // 16 MB (unrotated Q; rope fused in flash)
  float* Kw = Qw + (size_t)M * HQn * HDn;        //  4 MB (unrotated K)
  float* Vw = Kw + (size_t)M * HKVn * HDn;       //  4 MB
  float* Aw = Vw + (size_t)M * HKVn * HDn;       // 16 MB

  // Q-proj (split): 1024x4096x4096
  gemm_mfma<true, 128><<<dim3(DIMn / 128, M / 64, 1), 256, 0, stream>>>(
      x, wq, Qw, wq, Qw, DIMn, DIMn);
  // K-proj + V-proj fused (split, BN=64): 2 x 1024x1024x4096
  gemm_mfma<true, 64><<<dim3((HKVn * HDn) / 64, M / 64, 2), 256, 0, stream>>>(
      x, wk, Kw, wv, Vw, DIMn, HKVn * HDn);
  // MFMA flash attention with fused RoPE
  flash_attn_mfma<<<Bn * HQn * (Sn / 64), 256, 0, stream>>>(
      Qw, Kw, Vw, fc, fs, sidx, Aw);
  // O-proj (plain bf16): 1024x4096x4096
  gemm_mfma<false, 128><<<dim3(DIMn / 128, M / 64, 1), 256, 0, stream>>>(
      Aw, wo, out, wo, out, DIMn, DIMn);
}